// Round 2
// baseline (447.696 us; speedup 1.0000x reference)
//
#include <hip/hip_runtime.h>
#include <hip/hip_bf16.h>

// GLinear: out[p,o,d] = W_{seg(d)}[o,i] * x[p,i,d] + x[p,o,d]
// P=8192, C=256, D=16. seg: d=0->W00, 1..6->W10, 7..15->W11.
// R6 = R5 hardened. R5 theory: occupancy is reg-locked at 2 waves/SIMD
// (248 regs/wave), no cross-block overlap possible -> hide HBM latency
// INSIDE the block with an async glds pipeline. R5 container died; the
// only risky construct was the raw s_barrier + manual lgkmcnt sync.
// Key fact: in this schedule the barrier point has ZERO outstanding vmem
// (glds is waited at pack-top BEFORE the next barrier), so __syncthreads()
// -- whose implicit vmcnt(0) drain hits an empty queue -- is free. Use it.
//  - x staged fp32 via global_load_lds into wave-private LDS scratch (0 VGPR)
//  - pack phase reads own scratch (ds_read_b128) -> RNE bf16 -> swizzled tile
//  - bf16 tile double-buffered: ONE __syncthreads per chunk
//  - glds prefetch issued right after the barrier, waited only at next
//    pack-top: latency hidden under the whole compute phase
//  - launch_bounds(512,2): pin 256-reg cap (128 acc + ~110 VGPR fits)
//  - nontemporal out stores: don't evict x from L2/L3 (residual re-read)

#define C_DIM   256
#define D_DIM   16
#define P_TILE  16
#define KC      64
#define LDS_ROW 72     // bf16 elems per (p,d) row: 64 data + 8 pad

typedef __attribute__((ext_vector_type(8))) short  short8v;
typedef __attribute__((ext_vector_type(4))) float  float4v;
typedef __attribute__((ext_vector_type(4))) unsigned int uint4v;

// RNE fp32->bf16 pair pack
__device__ __forceinline__ unsigned int pack_bf16x2_rne(float lo, float hi) {
    unsigned int ul = __builtin_bit_cast(unsigned int, lo);
    unsigned int uh = __builtin_bit_cast(unsigned int, hi);
    ul = (ul + 0x7fffu + ((ul >> 16) & 1u)) >> 16;
    uh = (uh + 0x7fffu + ((uh >> 16) & 1u));
    return (ul & 0xffffu) | (uh & 0xffff0000u);
}

// Truncating pack: single v_perm_b32 (W path; error budget has 2.8x margin)
__device__ __forceinline__ unsigned int pack_bf16x2_tr(float lo, float hi) {
    return __builtin_amdgcn_perm(__builtin_bit_cast(unsigned int, hi),
                                 __builtin_bit_cast(unsigned int, lo),
                                 0x07060302u);
}

__device__ __forceinline__ short8v load_w_frag(const float* __restrict__ W, int row, int col) {
    const float* p = W + (size_t)row * C_DIM + col;
    float4v a = *(const float4v*)p;
    float4v b = *(const float4v*)(p + 4);
    uint4v u;
    u.x = pack_bf16x2_tr(a.x, a.y);
    u.y = pack_bf16x2_tr(a.z, a.w);
    u.z = pack_bf16x2_tr(b.x, b.y);
    u.w = pack_bf16x2_tr(b.z, b.w);
    return __builtin_bit_cast(short8v, u);
}

// async 16B global -> LDS (dest is wave-uniform base + lane*16)
__device__ __forceinline__ void glds16(const float* g, float* l) {
    __builtin_amdgcn_global_load_lds(
        (const __attribute__((address_space(1))) void*)g,
        (__attribute__((address_space(3))) void*)l,
        16, 0, 0);
}

__global__ __launch_bounds__(512, 2) void glinear_kernel(
    const float* __restrict__ x, const float* __restrict__ W00,
    const float* __restrict__ W10, const float* __restrict__ W11,
    float* __restrict__ out)
{
    // fp32 staging scratch: 64 regions of 1 KiB; region (it,k,w) is written by
    // wave w's glds (lane l at +16*l) and read back ONLY by wave w -> wave-private,
    // needs no barrier, only vmcnt(0) on own loads.
    __shared__ __align__(16) float f32s[64 * 256];                              // 65536 B
    // bf16 x-tile, double-buffered: elem (p,i,d) at row p*16+d,
    // col = ((i>>3)^(p&7))*8 + (i&7)
    __shared__ __align__(16) unsigned short ls[2][P_TILE * D_DIM * LDS_ROW];    // 73728 B

    const int t    = threadIdx.x;
    const int lane = t & 63;
    const int w    = t >> 6;          // wave 0..7 -> o in [32w, 32w+32)
    const int lm   = lane & 15;
    const int quad = lane >> 4;

    const int pbase = blockIdx.x * P_TILE;

    float4v acc[2][16];
    const float4v fzero = {0.f, 0.f, 0.f, 0.f};
    #pragma unroll
    for (int a = 0; a < 2; ++a)
        #pragma unroll
        for (int b = 0; b < 16; ++b) acc[a][b] = fzero;

    // staging coords: 512 threads cover 16p x 64i x 16d per chunk
    const int d4    = t & 3;              // d-group of 4
    const int ip    = (t >> 2) & 31;      // i-pair index (chunk-local)
    const int pq    = t >> 7;             // 0..3 (wave-uniform: w>>1)
    const int i_loc = ip * 2;

    const int orow0 = w * 32 + lm;        // W rows for B-fragments
    const int orow1 = w * 32 + 16 + lm;

    // ---- async stage of one 64-i chunk into wave-private f32 scratch ----
    auto stage_chunk = [&](int ic) {
        #pragma unroll
        for (int it = 0; it < 4; ++it) {
            const float* src = x + ((size_t)(pbase + pq + it * 4) * C_DIM
                                    + (ic * KC + i_loc)) * D_DIM + d4 * 4;
            glds16(src,         &f32s[((it * 2 + 0) * 8 + w) << 8]);
            glds16(src + D_DIM, &f32s[((it * 2 + 1) * 8 + w) << 8]);
        }
    };

    stage_chunk(0);   // prologue: chunk 0 in flight

    for (int ic = 0; ic < 4; ++ic) {
        const int ibase = ic * KC;
        const int ib    = ic & 1;

        // wait own glds (steady state: latency was covered by previous compute)
        asm volatile("s_waitcnt vmcnt(0)" ::: "memory");

        // ---- pack: LDS fp32 (own regions) -> bf16 tile ls[ib] ----
        #pragma unroll
        for (int it = 0; it < 4; ++it) {
            const int p = pq + it * 4;
            float4v a = *(const float4v*)&f32s[((((it * 2 + 0) * 8 + w) << 8)) + lane * 4];
            float4v b = *(const float4v*)&f32s[((((it * 2 + 1) * 8 + w) << 8)) + lane * 4];
            const int g = (i_loc >> 3) ^ (p & 7);
            const int e = i_loc & 7;
            const int base = (p * D_DIM + d4 * 4) * LDS_ROW + g * 8 + e;
            #pragma unroll
            for (int dj = 0; dj < 4; ++dj) {
                *(unsigned int*)(&ls[ib][base + dj * LDS_ROW]) = pack_bf16x2_rne(a[dj], b[dj]);
            }
        }
        // tile visible to all waves; implicit vmcnt(0) drain hits an empty
        // queue (all glds already waited above) -> no pipeline loss
        __syncthreads();

        // ---- prefetch next chunk (async, in flight under the compute phase) ----
        if (ic < 3) stage_chunk(ic + 1);
        asm volatile("" ::: "memory");   // pin: glds issue must precede compute

        // ---- compute: 2 k-steps of 32 ----
        #pragma unroll
        for (int ks = 0; ks < 2; ++ks) {
            const int col = ibase + ks * 32 + quad * 8;
            const int gq  = ((ks * 4 + quad) ^ (lm & 7));
            const unsigned short* brow = &ls[ib][lm * D_DIM * LDS_ROW + gq * 8];

            short8v f00_0 = load_w_frag(W00, orow0, col);
            short8v f00_1 = load_w_frag(W00, orow1, col);
            short8v f10_0 = load_w_frag(W10, orow0, col);
            short8v f10_1 = load_w_frag(W10, orow1, col);
            short8v f11_0 = load_w_frag(W11, orow0, col);
            short8v f11_1 = load_w_frag(W11, orow1, col);

            #pragma unroll
            for (int dd = 0; dd < 16; ++dd) {
                short8v xf = *(const short8v*)(brow + dd * LDS_ROW);
                short8v w0 = (dd == 0) ? f00_0 : (dd <= 6) ? f10_0 : f11_0;
                short8v w1 = (dd == 0) ? f00_1 : (dd <= 6) ? f10_1 : f11_1;
                // A = x (m=p), B = W (n=o) -> D row=p(quad*4+reg), col=o(lane&15)
                acc[0][dd] = __builtin_amdgcn_mfma_f32_16x16x32_bf16(xf, w0, acc[0][dd], 0, 0, 0);
                acc[1][dd] = __builtin_amdgcn_mfma_f32_16x16x32_bf16(xf, w1, acc[1][dd], 0, 0, 0);
            }
        }
        // no trailing barrier: double buffer + next iteration's barrier cover reuse
    }

    // ---- epilogue: direct stores. lane -> (p = quad*4+r, o = w*32+ot*16+lm) ----
    // float4 along d; lanes of a quad span 16 consecutive o; residual x re-read
    // hits L2/L3 (x staged once); out stores nontemporal (write-only stream).
    #pragma unroll
    for (int ot = 0; ot < 2; ++ot) {
        const int o = w * 32 + ot * 16 + lm;
        #pragma unroll
        for (int r = 0; r < 4; ++r) {
            const int p = pbase + quad * 4 + r;
            const size_t off = (size_t)p * (C_DIM * D_DIM) + (size_t)o * D_DIM;
            #pragma unroll
            for (int g = 0; g < 4; ++g) {
                float4v v;
                v.x = acc[ot][g * 4 + 0][r];
                v.y = acc[ot][g * 4 + 1][r];
                v.z = acc[ot][g * 4 + 2][r];
                v.w = acc[ot][g * 4 + 3][r];
                float4v xr = *(const float4v*)(x + off + g * 4);
                __builtin_nontemporal_store(v + xr, (float4v*)(out + off + g * 4));
            }
        }
    }
}

extern "C" void kernel_launch(void* const* d_in, const int* in_sizes, int n_in,
                              void* d_out, int out_size, void* d_ws, size_t ws_size,
                              hipStream_t stream) {
    const float* x   = (const float*)d_in[0];
    const float* W00 = (const float*)d_in[1];
    const float* W10 = (const float*)d_in[2];
    const float* W11 = (const float*)d_in[3];
    float* out = (float*)d_out;

    dim3 grid(512);    // one block per 16-row p-tile; x staged exactly once
    dim3 block(512);
    hipLaunchKernelGGL(glinear_kernel, grid, block, 0, stream, x, W00, W10, W11, out);
}

// Round 3
// 304.493 us; speedup vs baseline: 1.4703x; 1.4703x over previous
//
#include <hip/hip_runtime.h>
#include <hip/hip_bf16.h>

// GLinear: out[p,o,d] = W_{seg(d)}[o,i] * x[p,i,d] + x[p,o,d]
// P=8192, C=256, D=16. seg: d=0->W00, 1..6->W10, 7..15->W11.
// R7. R6 post-mortem:
//  (a) nontemporal epilogue stores caused 2.5x HBM write amplification
//      (WRITE_SIZE 132->331MB): 4x16B partial-line stores per 64B line
//      lose L2 write-combining under nt. REVERTED to plain stores.
//  (b) async glds pipeline was neutral: vmcnt is ONE in-order counter, so
//      the compute phase's global W-fragment loads forced a full drain of
//      the glds prefetch before the first MFMA. FIX: make the steady-state
//      loop contain ZERO global loads except glds -- W is preloaded into
//      registers for ALL chunks (24 frags = 96 VGPR), which requires
//      16 o-columns per wave (acc 128->64). Block covers 16p x 128o;
//      grid 1024, pairs (bid>>1 = ptile, bid&1 = ohalf) read the same
//      x-tile near-simultaneously -> 2nd read is an L3 hit, not HBM.
//  - x staged fp32 via global_load_lds into wave-private LDS scratch (0 VGPR)
//  - pack: own-scratch ds_read -> RNE bf16 -> swizzled dbuf tile
//  - ONE __syncthreads per chunk; its implicit vmcnt drain hits an empty
//    queue (own glds already waited at pack-top)
//  - compute: pure ds_read+MFMA vs register W -> glds(ic+1) stays in flight
//  - chunk loop fully unrolled so wf[ic][ks][mat] is statically indexed

#define C_DIM   256
#define D_DIM   16
#define P_TILE  16
#define KC      64
#define LDS_ROW 72     // bf16 elems per (p,d) row: 64 data + 8 pad

typedef __attribute__((ext_vector_type(8))) short  short8v;
typedef __attribute__((ext_vector_type(4))) float  float4v;
typedef __attribute__((ext_vector_type(4))) unsigned int uint4v;

// RNE fp32->bf16 pair pack
__device__ __forceinline__ unsigned int pack_bf16x2_rne(float lo, float hi) {
    unsigned int ul = __builtin_bit_cast(unsigned int, lo);
    unsigned int uh = __builtin_bit_cast(unsigned int, hi);
    ul = (ul + 0x7fffu + ((ul >> 16) & 1u)) >> 16;
    uh = (uh + 0x7fffu + ((uh >> 16) & 1u));
    return (ul & 0xffffu) | (uh & 0xffff0000u);
}

// Truncating pack: single v_perm_b32 (W path; error budget has 2.8x margin)
__device__ __forceinline__ unsigned int pack_bf16x2_tr(float lo, float hi) {
    return __builtin_amdgcn_perm(__builtin_bit_cast(unsigned int, hi),
                                 __builtin_bit_cast(unsigned int, lo),
                                 0x07060302u);
}

__device__ __forceinline__ short8v load_w_frag(const float* __restrict__ W, int row, int col) {
    const float* p = W + (size_t)row * C_DIM + col;
    float4v a = *(const float4v*)p;
    float4v b = *(const float4v*)(p + 4);
    uint4v u;
    u.x = pack_bf16x2_tr(a.x, a.y);
    u.y = pack_bf16x2_tr(a.z, a.w);
    u.z = pack_bf16x2_tr(b.x, b.y);
    u.w = pack_bf16x2_tr(b.z, b.w);
    return __builtin_bit_cast(short8v, u);
}

// async 16B global -> LDS (dest is wave-uniform base + lane*16)
__device__ __forceinline__ void glds16(const float* g, float* l) {
    __builtin_amdgcn_global_load_lds(
        (const __attribute__((address_space(1))) void*)g,
        (__attribute__((address_space(3))) void*)l,
        16, 0, 0);
}

__global__ __launch_bounds__(512, 2) void glinear_kernel(
    const float* __restrict__ x, const float* __restrict__ W00,
    const float* __restrict__ W10, const float* __restrict__ W11,
    float* __restrict__ out)
{
    // fp32 staging scratch: 64 regions of 1 KiB; region (it,k,w) is written by
    // wave w's glds (lane l at +16*l) and read back ONLY by wave w -> wave-private,
    // needs no barrier, only vmcnt on own loads.
    __shared__ __align__(16) float f32s[64 * 256];                              // 65536 B
    // bf16 x-tile, double-buffered: elem (p,i,d) at row p*16+d,
    // col = ((i_loc>>3)^(p&7))*8 + (i_loc&7), i_loc chunk-local
    __shared__ __align__(16) unsigned short ls[2][P_TILE * D_DIM * LDS_ROW];    // 73728 B

    const int t    = threadIdx.x;
    const int lane = t & 63;
    const int w    = t >> 6;          // wave 0..7 -> 16 o-cols each
    const int lm   = lane & 15;
    const int quad = lane >> 4;

    const int ohalf = blockIdx.x & 1;
    const int pbase = (blockIdx.x >> 1) * P_TILE;
    const int obase = ohalf * 128 + w * 16;
    const int orow  = obase + lm;     // W row for this lane's B-fragments

    // staging coords: 512 threads cover 16p x 64i x 16d per chunk
    const int d4    = t & 3;              // d-group of 4
    const int ip    = (t >> 2) & 31;      // i-pair index (chunk-local)
    const int pq    = t >> 7;             // 0..3
    const int i_loc = ip * 2;

    // ---- W preload: ALL fragments for the whole kernel into registers ----
    // 4 chunks x 2 ksteps x 3 mats x 4 VGPR = 96 VGPRs. L2/L3-resident reads.
    short8v wf[4][2][3];
    #pragma unroll
    for (int ic = 0; ic < 4; ++ic) {
        #pragma unroll
        for (int ks = 0; ks < 2; ++ks) {
            const int col = ic * KC + ks * 32 + quad * 8;
            wf[ic][ks][0] = load_w_frag(W00, orow, col);
            wf[ic][ks][1] = load_w_frag(W10, orow, col);
            wf[ic][ks][2] = load_w_frag(W11, orow, col);
        }
    }
    asm volatile("" ::: "memory");   // keep glds(0) issue after W loads

    // ---- async stage of one 64-i chunk into wave-private f32 scratch ----
    auto stage_chunk = [&](int ic) {
        #pragma unroll
        for (int it = 0; it < 4; ++it) {
            const float* src = x + ((size_t)(pbase + pq + it * 4) * C_DIM
                                    + (ic * KC + i_loc)) * D_DIM + d4 * 4;
            glds16(src,         &f32s[((it * 2 + 0) * 8 + w) << 8]);
            glds16(src + D_DIM, &f32s[((it * 2 + 1) * 8 + w) << 8]);
        }
    };

    stage_chunk(0);   // prologue: chunk 0 in flight (overlaps nothing ahead of it)

    float4v acc[16];
    const float4v fzero = {0.f, 0.f, 0.f, 0.f};
    #pragma unroll
    for (int b = 0; b < 16; ++b) acc[b] = fzero;

    #pragma unroll
    for (int ic = 0; ic < 4; ++ic) {
        const int ib = ic & 1;

        // wait own glds (steady state: latency covered by previous compute)
        asm volatile("s_waitcnt vmcnt(0)" ::: "memory");

        // ---- pack: LDS fp32 (own regions) -> bf16 tile ls[ib] ----
        #pragma unroll
        for (int it = 0; it < 4; ++it) {
            const int p = pq + it * 4;
            float4v a = *(const float4v*)&f32s[((((it * 2 + 0) * 8 + w) << 8)) + lane * 4];
            float4v b = *(const float4v*)&f32s[((((it * 2 + 1) * 8 + w) << 8)) + lane * 4];
            const int g = (i_loc >> 3) ^ (p & 7);
            const int e = i_loc & 7;
            const int base = (p * D_DIM + d4 * 4) * LDS_ROW + g * 8 + e;
            #pragma unroll
            for (int dj = 0; dj < 4; ++dj) {
                *(unsigned int*)(&ls[ib][base + dj * LDS_ROW]) = pack_bf16x2_rne(a[dj], b[dj]);
            }
        }
        // tile visible to all waves; implicit vmcnt(0) drain hits an empty queue
        __syncthreads();

        // ---- prefetch next chunk: the ONLY vmem in flight during compute ----
        if (ic < 3) stage_chunk(ic + 1);
        asm volatile("" ::: "memory");   // pin: glds issue precedes compute

        // ---- compute: 2 k-steps of 32, pure ds_read + MFMA (no global) ----
        #pragma unroll
        for (int ks = 0; ks < 2; ++ks) {
            const int gq = ((ks * 4 + quad) ^ (lm & 7));
            const unsigned short* brow = &ls[ib][lm * D_DIM * LDS_ROW + gq * 8];

            #pragma unroll
            for (int dd = 0; dd < 16; ++dd) {
                short8v xf = *(const short8v*)(brow + dd * LDS_ROW);
                short8v wv = (dd == 0) ? wf[ic][ks][0]
                           : (dd <= 6) ? wf[ic][ks][1]
                                       : wf[ic][ks][2];
                // A = x (m=p), B = W (n=o) -> D row=p(quad*4+reg), col=o(lane&15)
                acc[dd] = __builtin_amdgcn_mfma_f32_16x16x32_bf16(xf, wv, acc[dd], 0, 0, 0);
            }
        }
        // no trailing barrier: double buffer + next iteration's barrier cover reuse
    }

    // ---- epilogue: plain stores (nt caused 2.5x write amplification in R6).
    // lane -> (p = quad*4+r, o = obase+lm); float4 along d; a quad's 16 lanes
    // span 16 consecutive o -> 4 g-stores complete each 64B line in L2.
    #pragma unroll
    for (int r = 0; r < 4; ++r) {
        const int p = pbase + quad * 4 + r;
        const int o = obase + lm;
        const size_t off = (size_t)p * (C_DIM * D_DIM) + (size_t)o * D_DIM;
        #pragma unroll
        for (int g = 0; g < 4; ++g) {
            float4v v;
            v.x = acc[g * 4 + 0][r];
            v.y = acc[g * 4 + 1][r];
            v.z = acc[g * 4 + 2][r];
            v.w = acc[g * 4 + 3][r];
            float4v xr = *(const float4v*)(x + off + g * 4);
            *(float4v*)(out + off + g * 4) = v + xr;
        }
    }
}

extern "C" void kernel_launch(void* const* d_in, const int* in_sizes, int n_in,
                              void* d_out, int out_size, void* d_ws, size_t ws_size,
                              hipStream_t stream) {
    const float* x   = (const float*)d_in[0];
    const float* W00 = (const float*)d_in[1];
    const float* W10 = (const float*)d_in[2];
    const float* W11 = (const float*)d_in[3];
    float* out = (float*)d_out;

    dim3 grid(1024);   // (bid>>1)=p-tile, (bid&1)=o-half; pairs adjacent in
    dim3 block(512);   // dispatch order -> 2nd x-tile read hits L3, not HBM
    hipLaunchKernelGGL(glinear_kernel, grid, block, 0, stream, x, W00, W10, W11, out);
}

// Round 5
// 279.535 us; speedup vs baseline: 1.6016x; 1.0893x over previous
//
#include <hip/hip_runtime.h>
#include <hip/hip_bf16.h>

// GLinear: out[p,o,d] = W_{seg(d)}[o,i] * x[p,i,d] + x[p,o,d]
// P=8192, C=256, D=16. seg: d=0->W00, 1..6->W10, 7..15->W11.
// R9 = R8 resubmission (container died twice with no test output; audit
// found no kernel-side hazard -- sync structure proven by R7's passing run,
// all bounds verified; infra flake suspected). Hardening: bounds guard in
// init_w_pack. R8 rationale:
//  (a) R7's W preload is a per-lane-row GATHER (64 lanes x 1KB stride = 64
//      cache lines per dwordx4), paid once per block-round.
//  (b) grid 1024 at 1 block/CU = 4 serial rounds re-paying W preload +
//      pipeline prologue/drain.
// Fixes:
//  - grid 256 persistent: 1 block/CU, each block = 1 o-half x 4 p-tiles.
//    W preload once; glds pipeline crosses p-tile boundaries (chunk0 of the
//    next tile issued before compute(c3)+epilogue -> ~2600cy cover).
//  - init kernel pre-packs W into d_ws as RNE-bf16 MFMA fragments, per-wave
//    contiguous -> main-kernel W preload = 24 fully-coalesced dwordx4/wave.
//    Fallback to direct fp32 gather if workspace is unavailable.
//  - core pipeline (glds scratch staging, RNE pack, swizzled dbuf tile,
//    1 barrier/chunk, plain epilogue stores) byte-identical to verified R7.

#define C_DIM   256
#define D_DIM   16
#define P_TILE  16
#define KC      64
#define LDS_ROW 72     // bf16 elems per (p,d) row: 64 data + 8 pad
#define UNITS   4      // p-tiles per block
#define NFRAG   (2 * 8 * 24 * 64)   // (oh, w, frag, lane) fragment-lanes
#define WS_NEEDED (NFRAG * 16)      // 393216 B

typedef __attribute__((ext_vector_type(8))) short  short8v;
typedef __attribute__((ext_vector_type(4))) float  float4v;
typedef __attribute__((ext_vector_type(4))) unsigned int uint4v;

// RNE fp32->bf16 pair pack
__device__ __forceinline__ unsigned int pack_bf16x2_rne(float lo, float hi) {
    unsigned int ul = __builtin_bit_cast(unsigned int, lo);
    unsigned int uh = __builtin_bit_cast(unsigned int, hi);
    ul = (ul + 0x7fffu + ((ul >> 16) & 1u)) >> 16;
    uh = (uh + 0x7fffu + ((uh >> 16) & 1u));
    return (ul & 0xffffu) | (uh & 0xffff0000u);
}

// Truncating pack (fallback W path only; error budget has 2.8x margin)
__device__ __forceinline__ unsigned int pack_bf16x2_tr(float lo, float hi) {
    return __builtin_amdgcn_perm(__builtin_bit_cast(unsigned int, hi),
                                 __builtin_bit_cast(unsigned int, lo),
                                 0x07060302u);
}

__device__ __forceinline__ short8v load_w_frag(const float* __restrict__ W, int row, int col) {
    const float* p = W + (size_t)row * C_DIM + col;
    float4v a = *(const float4v*)p;
    float4v b = *(const float4v*)(p + 4);
    uint4v u;
    u.x = pack_bf16x2_tr(a.x, a.y);
    u.y = pack_bf16x2_tr(a.z, a.w);
    u.z = pack_bf16x2_tr(b.x, b.y);
    u.w = pack_bf16x2_tr(b.z, b.w);
    return __builtin_bit_cast(short8v, u);
}

// async 16B global -> LDS (dest is wave-uniform base + lane*16)
__device__ __forceinline__ void glds16(const float* g, float* l) {
    __builtin_amdgcn_global_load_lds(
        (const __attribute__((address_space(1))) void*)g,
        (__attribute__((address_space(3))) void*)l,
        16, 0, 0);
}

// ---- init: pack W into per-wave-contiguous bf16 fragments in workspace ----
// layout: frag (oh, w, f=ic*6+ks*3+mat), lane l -> 16B at
//   ws[(((oh*8 + w)*24 + f)*64 + l) * 16B]
// lane l holds cols [ic*64+ks*32+(l>>4)*8, +8) of row (oh*128+w*16+(l&15)),
// RNE-packed pairwise -- exactly the MFMA B-fragment the main kernel needs.
__global__ __launch_bounds__(256, 4) void init_w_pack(
    const float* __restrict__ W00, const float* __restrict__ W10,
    const float* __restrict__ W11, uint4v* __restrict__ ws)
{
    const int tid = blockIdx.x * 256 + threadIdx.x;     // 24576 threads
    if (tid >= NFRAG) return;                           // defensive bound
    const int l   = tid & 63;
    int idx = tid >> 6;
    const int f  = idx % 24;
    idx /= 24;
    const int w  = idx & 7;
    const int oh = idx >> 3;
    const int mat = f % 3;
    const int ks  = (f / 3) & 1;
    const int ic  = f / 6;
    const float* Wm = (mat == 0) ? W00 : (mat == 1) ? W10 : W11;
    const int row = oh * 128 + w * 16 + (l & 15);
    const int col = ic * KC + ks * 32 + (l >> 4) * 8;
    const float* p = Wm + (size_t)row * C_DIM + col;
    float4v a = *(const float4v*)p;
    float4v b = *(const float4v*)(p + 4);
    uint4v u;
    u.x = pack_bf16x2_rne(a.x, a.y);
    u.y = pack_bf16x2_rne(a.z, a.w);
    u.z = pack_bf16x2_rne(b.x, b.y);
    u.w = pack_bf16x2_rne(b.z, b.w);
    ws[tid] = u;
}

__global__ __launch_bounds__(512, 2) void glinear_kernel(
    const float* __restrict__ x, const float* __restrict__ W00,
    const float* __restrict__ W10, const float* __restrict__ W11,
    float* __restrict__ out, const short8v* __restrict__ wpack, int use_ws)
{
    // fp32 staging scratch: 64 regions of 1 KiB; region (it,k,w) written by
    // wave w's glds and read ONLY by wave w -> wave-private, no barrier needed.
    __shared__ __align__(16) float f32s[64 * 256];                              // 65536 B
    // bf16 x-tile, double-buffered: elem (p,i,d) at row p*16+d,
    // col = ((i_loc>>3)^(p&7))*8 + (i_loc&7), i_loc chunk-local
    __shared__ __align__(16) unsigned short ls[2][P_TILE * D_DIM * LDS_ROW];    // 73728 B

    const int t    = threadIdx.x;
    const int lane = t & 63;
    const int w    = t >> 6;          // wave 0..7 -> 16 o-cols each
    const int lm   = lane & 15;
    const int quad = lane >> 4;

    const int oh    = blockIdx.x & 1;
    const int pg    = blockIdx.x >> 1;        // 0..127, 4 p-tiles each
    const int obase = oh * 128 + w * 16;
    const int orow  = obase + lm;

    // staging coords: 512 threads cover 16p x 64i x 16d per chunk
    const int d4    = t & 3;
    const int ip    = (t >> 2) & 31;
    const int pq    = t >> 7;
    const int i_loc = ip * 2;

    // ---- W preload: all 24 fragments for this (oh, w) into registers ----
    short8v wf[4][2][3];
    if (use_ws && wpack != nullptr) {
        // fully coalesced: each load = wave-contiguous 1KB
        const short8v* wbase = wpack + ((size_t)(oh * 8 + w) * 24) * 64 + lane;
        #pragma unroll
        for (int ic = 0; ic < 4; ++ic)
            #pragma unroll
            for (int ks = 0; ks < 2; ++ks)
                #pragma unroll
                for (int mat = 0; mat < 3; ++mat)
                    wf[ic][ks][mat] = wbase[(size_t)(ic * 6 + ks * 3 + mat) * 64];
    } else {
        // fallback: direct fp32 gather (verified R7 path)
        #pragma unroll
        for (int ic = 0; ic < 4; ++ic)
            #pragma unroll
            for (int ks = 0; ks < 2; ++ks) {
                const int col = ic * KC + ks * 32 + quad * 8;
                wf[ic][ks][0] = load_w_frag(W00, orow, col);
                wf[ic][ks][1] = load_w_frag(W10, orow, col);
                wf[ic][ks][2] = load_w_frag(W11, orow, col);
            }
    }
    asm volatile("" ::: "memory");   // keep glds(0) issue after W loads

    // ---- async stage of one 64-i chunk into wave-private f32 scratch ----
    auto stage_chunk = [&](int pb, int ic) {
        #pragma unroll
        for (int it = 0; it < 4; ++it) {
            const float* src = x + ((size_t)(pb + pq + it * 4) * C_DIM
                                    + (ic * KC + i_loc)) * D_DIM + d4 * 4;
            glds16(src,         &f32s[((it * 2 + 0) * 8 + w) << 8]);
            glds16(src + D_DIM, &f32s[((it * 2 + 1) * 8 + w) << 8]);
        }
    };

    stage_chunk(pg * UNITS * P_TILE, 0);   // prologue: unit 0, chunk 0

    for (int u = 0; u < UNITS; ++u) {
        const int pbase = (pg * UNITS + u) * P_TILE;

        float4v acc[16];
        const float4v fzero = {0.f, 0.f, 0.f, 0.f};
        #pragma unroll
        for (int b = 0; b < 16; ++b) acc[b] = fzero;

        #pragma unroll
        for (int ic = 0; ic < 4; ++ic) {
            const int ib = ic & 1;

            // wait own glds (steady state: latency covered by prior compute/epi)
            asm volatile("s_waitcnt vmcnt(0)" ::: "memory");

            // ---- pack: LDS fp32 (own regions) -> bf16 tile ls[ib] ----
            #pragma unroll
            for (int it = 0; it < 4; ++it) {
                const int p = pq + it * 4;
                float4v a = *(const float4v*)&f32s[((((it * 2 + 0) * 8 + w) << 8)) + lane * 4];
                float4v b = *(const float4v*)&f32s[((((it * 2 + 1) * 8 + w) << 8)) + lane * 4];
                const int g = (i_loc >> 3) ^ (p & 7);
                const int e = i_loc & 7;
                const int base = (p * D_DIM + d4 * 4) * LDS_ROW + g * 8 + e;
                #pragma unroll
                for (int dj = 0; dj < 4; ++dj) {
                    *(unsigned int*)(&ls[ib][base + dj * LDS_ROW]) = pack_bf16x2_rne(a[dj], b[dj]);
                }
            }
            // implicit vmcnt(0) drain hits an empty queue (glds waited above)
            __syncthreads();

            // ---- prefetch next chunk (crosses unit boundary seamlessly) ----
            if (ic < 3)               stage_chunk(pbase, ic + 1);
            else if (u < UNITS - 1)   stage_chunk(pbase + P_TILE, 0);
            asm volatile("" ::: "memory");   // pin: glds issue precedes compute

            // ---- compute: 2 k-steps of 32, pure ds_read + MFMA ----
            #pragma unroll
            for (int ks = 0; ks < 2; ++ks) {
                const int gq = ((ks * 4 + quad) ^ (lm & 7));
                const unsigned short* brow = &ls[ib][lm * D_DIM * LDS_ROW + gq * 8];

                #pragma unroll
                for (int dd = 0; dd < 16; ++dd) {
                    short8v xf = *(const short8v*)(brow + dd * LDS_ROW);
                    short8v wv = (dd == 0) ? wf[ic][ks][0]
                               : (dd <= 6) ? wf[ic][ks][1]
                                           : wf[ic][ks][2];
                    // A = x (m=p), B = W (n=o) -> D row=p(quad*4+reg), col=o(lm)
                    acc[dd] = __builtin_amdgcn_mfma_f32_16x16x32_bf16(xf, wv, acc[dd], 0, 0, 0);
                }
            }
        }

        // ---- epilogue: plain stores; residual x re-read is an L2/L3 hit ----
        #pragma unroll
        for (int r = 0; r < 4; ++r) {
            const int p = pbase + quad * 4 + r;
            const int o = obase + lm;
            const size_t off = (size_t)p * (C_DIM * D_DIM) + (size_t)o * D_DIM;
            #pragma unroll
            for (int g = 0; g < 4; ++g) {
                float4v v;
                v.x = acc[g * 4 + 0][r];
                v.y = acc[g * 4 + 1][r];
                v.z = acc[g * 4 + 2][r];
                v.w = acc[g * 4 + 3][r];
                float4v xr = *(const float4v*)(x + off + g * 4);
                *(float4v*)(out + off + g * 4) = v + xr;
            }
        }
    }
}

extern "C" void kernel_launch(void* const* d_in, const int* in_sizes, int n_in,
                              void* d_out, int out_size, void* d_ws, size_t ws_size,
                              hipStream_t stream) {
    const float* x   = (const float*)d_in[0];
    const float* W00 = (const float*)d_in[1];
    const float* W10 = (const float*)d_in[2];
    const float* W11 = (const float*)d_in[3];
    float* out = (float*)d_out;

    const int use_ws = (d_ws != nullptr && ws_size >= WS_NEEDED) ? 1 : 0;
    if (use_ws) {
        hipLaunchKernelGGL(init_w_pack, dim3(96), dim3(256), 0, stream,
                           W00, W10, W11, (uint4v*)d_ws);
    }
    // grid 256: 1 persistent block per CU; (bid>>1)=p-group of 4 tiles,
    // (bid&1)=o-half; paired blocks run in lockstep -> x 2nd read hits L2/L3.
    hipLaunchKernelGGL(glinear_kernel, dim3(256), dim3(512), 0, stream,
                       x, W00, W10, W11, out, (const short8v*)d_ws, use_ws);
}